// Round 2
// baseline (443.518 us; speedup 1.0000x reference)
//
#include <hip/hip_runtime.h>

#define N_NODES 50000
#define N_EDGES 600000
#define N_GRAPHS 512

// ---------------- index-width detect (int32 vs int64 input layout) ----------
__global__ void detect_kernel(const int* __restrict__ ei, int* __restrict__ flag) {
    int lane = threadIdx.x;                 // 64 lanes
    int v = ei[2 * lane + 1];               // odd words: int64 high-words OR int32 src[2k+1]
    unsigned long long nz = __ballot(v != 0);
    if (lane == 0) *flag = (nz == 0ull) ? 1 : 0;   // all zero -> int64
}

__device__ __forceinline__ int idx_at(const int* __restrict__ a, int i, int wide) {
    return wide ? a[2 * i] : a[i];          // little-endian low word; values < 2^31
}

// ---------------- CSR build ----------------
__global__ void hist_kernel(const int* __restrict__ ei, const int* __restrict__ flag,
                            int* __restrict__ cnt) {
    int e = blockIdx.x * 256 + threadIdx.x;
    if (e >= N_EDGES) return;
    int w = *flag;
    const int* dst = ei + (w ? 2 * N_EDGES : N_EDGES);
    atomicAdd(&cnt[idx_at(dst, e, w)], 1);
}

__global__ void scan1(const int* __restrict__ cnt, int* __restrict__ excl,
                      int* __restrict__ bsum) {
    __shared__ int s[256];
    int tid = threadIdx.x;
    int i = blockIdx.x * 256 + tid;
    int v = (i < N_NODES) ? cnt[i] : 0;
    s[tid] = v; __syncthreads();
    for (int off = 1; off < 256; off <<= 1) {
        int t = (tid >= off) ? s[tid - off] : 0;
        __syncthreads();
        s[tid] += t;
        __syncthreads();
    }
    if (i < N_NODES) excl[i] = s[tid] - v;
    if (tid == 255) bsum[blockIdx.x] = s[255];
}

__global__ void scan2(int* __restrict__ bsum, int nb) {
    __shared__ int s[256];
    int tid = threadIdx.x;
    int v = (tid < nb) ? bsum[tid] : 0;
    s[tid] = v; __syncthreads();
    for (int off = 1; off < 256; off <<= 1) {
        int t = (tid >= off) ? s[tid - off] : 0;
        __syncthreads();
        s[tid] += t;
        __syncthreads();
    }
    if (tid < nb) bsum[tid] = s[tid] - v;
}

__global__ void scan3(int* __restrict__ offsets, const int* __restrict__ bsum,
                      int* __restrict__ cursor) {
    int i = blockIdx.x * 256 + threadIdx.x;
    if (i < N_NODES) {
        int off = offsets[i] + bsum[i >> 8];
        offsets[i] = off;
        cursor[i] = off;
    }
    if (i == 0) offsets[N_NODES] = N_EDGES;
}

__global__ void scatter_kernel(const int* __restrict__ ei, const int* __restrict__ flag,
                               int* __restrict__ cursor, int* __restrict__ ssrc) {
    int e = blockIdx.x * 256 + threadIdx.x;
    if (e >= N_EDGES) return;
    int w = *flag;
    const int* src = ei;
    const int* dst = ei + (w ? 2 * N_EDGES : N_EDGES);
    int d = idx_at(dst, e, w);
    int pos = atomicAdd(&cursor[d], 1);
    ssrc[pos] = idx_at(src, e, w);
}

// ---------------- aggregation: h = x + sum_{j->i} x[j] ----------------
__global__ void agg_kernel(const float* __restrict__ x, const int* __restrict__ offsets,
                           const int* __restrict__ ssrc, float* __restrict__ h) {
    int node = blockIdx.x * 4 + (threadIdx.x >> 6);
    int lane = threadIdx.x & 63;
    if (node >= N_NODES) return;
    const float2* xr = (const float2*)x;
    float2 acc = xr[(size_t)node * 64 + lane];
    int b = offsets[node], e = offsets[node + 1];
    for (int t = b; t < e; ++t) {
        int s = ssrc[t];
        float2 v = xr[(size_t)s * 64 + lane];
        acc.x += v.x; acc.y += v.y;
    }
    ((float2*)h)[(size_t)node * 64 + lane] = acc;
}

// ---------------- fp32 tiled GEMM: C = [ReLU](A[M,K] @ W[K,N] + b) ----------
template <int RELU>
__global__ __launch_bounds__(256) void gemm_kernel(const float* __restrict__ A,
                                                   const float* __restrict__ W,
                                                   const float* __restrict__ bias,
                                                   float* __restrict__ C,
                                                   int M, int K, int N) {
    __shared__ float As[16][68];   // [k][m], stride 68 floats (272B, 16B-aligned rows)
    __shared__ float Ws[16][68];   // [k][n]
    int tid = threadIdx.x;
    int tx = tid & 15, ty = tid >> 4;
    int bm = blockIdx.y * 64;
    int bn = blockIdx.x * 64;

    int lr  = tid >> 2;            // 0..63 : A row within tile
    int lkq = (tid & 3) * 4;       // k quad
    int wk  = tid >> 4;            // 0..15 : W k row
    int wn  = (tid & 15) * 4;      // col quad

    float acc[4][4] = {};
    for (int k0 = 0; k0 < K; k0 += 16) {
        int arow = bm + lr; if (arow >= M) arow = M - 1;     // clamp (safe read)
        float4 a4 = *(const float4*)&A[(size_t)arow * K + k0 + lkq];
        As[lkq + 0][lr] = a4.x; As[lkq + 1][lr] = a4.y;
        As[lkq + 2][lr] = a4.z; As[lkq + 3][lr] = a4.w;
        float4 w4 = *(const float4*)&W[(size_t)(k0 + wk) * N + bn + wn];
        *(float4*)&Ws[wk][wn] = w4;
        __syncthreads();
#pragma unroll
        for (int kk = 0; kk < 16; ++kk) {
            float4 av = *(const float4*)&As[kk][ty * 4];
            float4 bv = *(const float4*)&Ws[kk][tx * 4];
            float a_[4] = {av.x, av.y, av.z, av.w};
            float b_[4] = {bv.x, bv.y, bv.z, bv.w};
#pragma unroll
            for (int i = 0; i < 4; ++i)
#pragma unroll
                for (int j = 0; j < 4; ++j)
                    acc[i][j] = fmaf(a_[i], b_[j], acc[i][j]);
        }
        __syncthreads();
    }
    float4 bv = *(const float4*)&bias[bn + tx * 4];
    float bb[4] = {bv.x, bv.y, bv.z, bv.w};
#pragma unroll
    for (int i = 0; i < 4; ++i) {
        int row = bm + ty * 4 + i;
        if (row < M) {
            float4 o;
            float* op = (float*)&o;
#pragma unroll
            for (int j = 0; j < 4; ++j) {
                float v = acc[i][j] + bb[j];
                if (RELU) v = fmaxf(v, 0.0f);
                op[j] = v;
            }
            *(float4*)&C[(size_t)row * N + bn + tx * 4] = o;
        }
    }
}

// ---------------- global add pool ----------------
__global__ void pool_kernel(const float* __restrict__ x, const int* __restrict__ batch,
                            const int* __restrict__ flag, float* __restrict__ out) {
    int idx = blockIdx.x * 256 + threadIdx.x;
    int node = idx >> 6;
    int c = idx & 63;
    if (node >= N_NODES) return;
    int w = *flag;
    int g = idx_at(batch, node, w);
    atomicAdd(&out[(size_t)g * 64 + c], x[(size_t)node * 64 + c]);
}

extern "C" void kernel_launch(void* const* d_in, const int* in_sizes, int n_in,
                              void* d_out, int out_size, void* d_ws, size_t ws_size,
                              hipStream_t stream) {
    const float* x     = (const float*)d_in[0];
    const int*   ei    = (const int*)d_in[1];
    const int*   batch = (const int*)d_in[2];
    const float* w1[3] = {(const float*)d_in[3], (const float*)d_in[7],  (const float*)d_in[11]};
    const float* b1[3] = {(const float*)d_in[4], (const float*)d_in[8],  (const float*)d_in[12]};
    const float* w2[3] = {(const float*)d_in[5], (const float*)d_in[9],  (const float*)d_in[13]};
    const float* b2[3] = {(const float*)d_in[6], (const float*)d_in[10], (const float*)d_in[14]};
    float* out = (float*)d_out;

    char* ws = (char*)d_ws;
    int*   cursor  = (int*)(ws + 0);          // 50000 ints (also histogram counts)
    int*   offsets = (int*)(ws + 200192);     // 50001 ints
    int*   bsum    = (int*)(ws + 400640);     // 196 ints
    int*   flag    = (int*)(ws + 401664);     // 1 int
    int*   ssrc    = (int*)(ws + 401920);     // 600000 ints
    float* bufA    = (float*)(ws + 2801920);  // 50000*128 f32
    float* bufB    = (float*)(ws + 28401920); // 50000*128 f32

    detect_kernel<<<1, 64, 0, stream>>>(ei, flag);

    (void)hipMemsetAsync(cursor, 0, N_NODES * sizeof(int), stream);
    hist_kernel<<<(N_EDGES + 255) / 256, 256, 0, stream>>>(ei, flag, cursor);
    scan1<<<196, 256, 0, stream>>>(cursor, offsets, bsum);
    scan2<<<1, 256, 0, stream>>>(bsum, 196);
    scan3<<<196, 256, 0, stream>>>(offsets, bsum, cursor);
    scatter_kernel<<<(N_EDGES + 255) / 256, 256, 0, stream>>>(ei, flag, cursor, ssrc);

    // Layer 0: x(in) -> A=h -> B=relu(h@w1+b1) -> A=relu(B@w2+b2)
    agg_kernel<<<12500, 256, 0, stream>>>(x, offsets, ssrc, bufA);
    gemm_kernel<1><<<dim3(2, 782), 256, 0, stream>>>(bufA, w1[0], b1[0], bufB, N_NODES, 128, 128);
    gemm_kernel<1><<<dim3(2, 782), 256, 0, stream>>>(bufB, w2[0], b2[0], bufA, N_NODES, 128, 128);
    // Layer 1: x=A -> B=h -> A -> B
    agg_kernel<<<12500, 256, 0, stream>>>(bufA, offsets, ssrc, bufB);
    gemm_kernel<1><<<dim3(2, 782), 256, 0, stream>>>(bufB, w1[1], b1[1], bufA, N_NODES, 128, 128);
    gemm_kernel<1><<<dim3(2, 782), 256, 0, stream>>>(bufA, w2[1], b2[1], bufB, N_NODES, 128, 128);
    // Layer 2: x=B -> A=h -> B=relu(A@w1+b1) [N=64] -> A=B@w2+b2 [N=64, no relu]
    agg_kernel<<<12500, 256, 0, stream>>>(bufB, offsets, ssrc, bufA);
    gemm_kernel<1><<<dim3(1, 782), 256, 0, stream>>>(bufA, w1[2], b1[2], bufB, N_NODES, 128, 64);
    gemm_kernel<0><<<dim3(1, 782), 256, 0, stream>>>(bufB, w2[2], b2[2], bufA, N_NODES, 64, 64);

    (void)hipMemsetAsync(out, 0, (size_t)out_size * sizeof(float), stream);
    pool_kernel<<<12500, 256, 0, stream>>>(bufA, batch, flag, out);
}

// Round 3
// 275.265 us; speedup vs baseline: 1.6112x; 1.6112x over previous
//
#include <hip/hip_runtime.h>

#define N_NODES 50000
#define N_EDGES 600000
#define N_GRAPHS 512

typedef unsigned int u32;
typedef unsigned short u16;
typedef __attribute__((ext_vector_type(8))) short bf16x8;
typedef __attribute__((ext_vector_type(4))) float f32x4;

__device__ __forceinline__ float bflo(u32 v) { return __uint_as_float(v << 16); }
__device__ __forceinline__ float bfhi(u32 v) { return __uint_as_float(v & 0xffff0000u); }
__device__ __forceinline__ u16 f2bf(float f) {
    u32 x = __float_as_uint(f);
    return (u16)((x + 0x7fffu + ((x >> 16) & 1u)) >> 16);
}

// ---------------- index-width detect (int32 vs int64 input layout) ----------
__global__ void detect_kernel(const int* __restrict__ ei, int* __restrict__ flag) {
    int lane = threadIdx.x;                 // 64 lanes
    int v = ei[2 * lane + 1];               // odd words: int64 high-words OR int32 src[2k+1]
    unsigned long long nz = __ballot(v != 0);
    if (lane == 0) *flag = (nz == 0ull) ? 1 : 0;   // all zero -> int64
}

__device__ __forceinline__ int idx_at(const int* __restrict__ a, int i, int wide) {
    return wide ? a[2 * i] : a[i];          // little-endian low word; values < 2^31
}

// ---------------- CSR build ----------------
__global__ void hist_kernel(const int* __restrict__ ei, const int* __restrict__ flag,
                            int* __restrict__ cnt) {
    int e = blockIdx.x * 256 + threadIdx.x;
    if (e >= N_EDGES) return;
    int w = *flag;
    const int* dst = ei + (w ? 2 * N_EDGES : N_EDGES);
    atomicAdd(&cnt[idx_at(dst, e, w)], 1);
}

__global__ void scan1(const int* __restrict__ cnt, int* __restrict__ excl,
                      int* __restrict__ bsum) {
    __shared__ int s[256];
    int tid = threadIdx.x;
    int i = blockIdx.x * 256 + tid;
    int v = (i < N_NODES) ? cnt[i] : 0;
    s[tid] = v; __syncthreads();
    for (int off = 1; off < 256; off <<= 1) {
        int t = (tid >= off) ? s[tid - off] : 0;
        __syncthreads();
        s[tid] += t;
        __syncthreads();
    }
    if (i < N_NODES) excl[i] = s[tid] - v;
    if (tid == 255) bsum[blockIdx.x] = s[255];
}

__global__ void scan2(int* __restrict__ bsum, int nb) {
    __shared__ int s[256];
    int tid = threadIdx.x;
    int v = (tid < nb) ? bsum[tid] : 0;
    s[tid] = v; __syncthreads();
    for (int off = 1; off < 256; off <<= 1) {
        int t = (tid >= off) ? s[tid - off] : 0;
        __syncthreads();
        s[tid] += t;
        __syncthreads();
    }
    if (tid < nb) bsum[tid] = s[tid] - v;
}

__global__ void scan3(int* __restrict__ offsets, const int* __restrict__ bsum,
                      int* __restrict__ cursor) {
    int i = blockIdx.x * 256 + threadIdx.x;
    if (i < N_NODES) {
        int off = offsets[i] + bsum[i >> 8];
        offsets[i] = off;
        cursor[i] = off;
    }
    if (i == 0) offsets[N_NODES] = N_EDGES;
}

__global__ void scatter_kernel(const int* __restrict__ ei, const int* __restrict__ flag,
                               int* __restrict__ cursor, int* __restrict__ ssrc) {
    int e = blockIdx.x * 256 + threadIdx.x;
    if (e >= N_EDGES) return;
    int w = *flag;
    const int* src = ei;
    const int* dst = ei + (w ? 2 * N_EDGES : N_EDGES);
    int d = idx_at(dst, e, w);
    int pos = atomicAdd(&cursor[d], 1);
    ssrc[pos] = idx_at(src, e, w);
}

// ---------------- converts ----------------
__global__ void cvt_x(const float* __restrict__ in, u16* __restrict__ out) {
    size_t i = (size_t)blockIdx.x * 256 + threadIdx.x;   // 1.6M threads, 4 elems each
    float4 v = *(const float4*)&in[i * 4];
    u32 o0 = (u32)f2bf(v.x) | ((u32)f2bf(v.y) << 16);
    u32 o1 = (u32)f2bf(v.z) | ((u32)f2bf(v.w) << 16);
    uint2 o; o.x = o0; o.y = o1;
    *(uint2*)&out[i * 4] = o;
}

// w [K][N] f32 -> wt [N][K] bf16 (tiled transpose)
__global__ void cvt_wt(const float* __restrict__ w, u16* __restrict__ wt, int K, int N) {
    __shared__ float tile[32][33];
    int bk = blockIdx.x * 32, bn = blockIdx.y * 32;
    int tx = threadIdx.x & 31, ty = threadIdx.x >> 5;   // 32 x 8
#pragma unroll
    for (int yy = 0; yy < 32; yy += 8)
        tile[ty + yy][tx] = w[(size_t)(bk + ty + yy) * N + bn + tx];
    __syncthreads();
#pragma unroll
    for (int yy = 0; yy < 32; yy += 8)
        wt[(size_t)(bn + ty + yy) * K + bk + tx] = f2bf(tile[tx][ty + yy]);
}

// ---------------- fused GIN layer: agg -> GEMM1(+b,ReLU) -> GEMM2(+b,[ReLU]) ----
template <int DOUT, int RELU_OUT, int F32OUT>
__global__ __launch_bounds__(512) void fused_layer(
    const u16* __restrict__ xb, const int* __restrict__ offsets,
    const int* __restrict__ ssrc,
    const u16* __restrict__ w1t, const float* __restrict__ b1,
    const u16* __restrict__ w2t, const float* __restrict__ b2,
    void* __restrict__ yout)
{
    __shared__ u16 hs[64 * 128];     // h tile, XOR-swizzled rows
    __shared__ u16 ts[64 * DOUT];    // relu(h@w1+b1) tile, XOR-swizzled
    const int tid = threadIdx.x;
    const int wave = tid >> 6, lane = tid & 63;
    const int base = blockIdx.x * 64;

    // ---- phase A: gather-aggregate, 8 nodes per wave, full row per wave ----
    for (int i = 0; i < 8; ++i) {
        int rr = wave * 8 + i;
        int node = base + rr;
        if (node >= N_NODES) break;              // wave-uniform
        u32 self = *(const u32*)(xb + ((size_t)node << 7) + 2 * lane);
        float ax = bflo(self), ay = bfhi(self);
        float ax2 = 0.f, ay2 = 0.f;
        int b0 = offsets[node];
        int deg = offsets[node + 1] - b0;
        int nid = (lane < deg) ? ssrc[b0 + lane] : 0;
        int dmain = deg > 64 ? 64 : deg;
        int j = 0;
        for (; j + 2 <= dmain; j += 2) {         // 2x unroll, independent accs
            int s0 = __shfl(nid, j);
            int s1 = __shfl(nid, j + 1);
            u32 v0 = *(const u32*)(xb + ((size_t)s0 << 7) + 2 * lane);
            u32 v1 = *(const u32*)(xb + ((size_t)s1 << 7) + 2 * lane);
            ax += bflo(v0); ay += bfhi(v0);
            ax2 += bflo(v1); ay2 += bfhi(v1);
        }
        if (j < dmain) {
            int s0 = __shfl(nid, j);
            u32 v0 = *(const u32*)(xb + ((size_t)s0 << 7) + 2 * lane);
            ax += bflo(v0); ay += bfhi(v0);
        }
        for (int t = b0 + 64; t < b0 + deg; ++t) {   // rare deg>64 tail
            int s0 = ssrc[t];
            u32 v0 = *(const u32*)(xb + ((size_t)s0 << 7) + 2 * lane);
            ax += bflo(v0); ay += bfhi(v0);
        }
        ax += ax2; ay += ay2;
        u32 pk = (u32)f2bf(ax) | ((u32)f2bf(ay) << 16);
        int c = (2 * lane) ^ ((rr & 7) << 3);
        *(u32*)&hs[rr * 128 + c] = pk;
    }
    __syncthreads();

    const int m = lane & 15;
    const int ko = (lane >> 4) * 8;
    const int rb = (wave & 3) * 16;               // row block (16 rows)
    const int cbase = (wave >> 2) * (DOUT / 2);   // col half
    constexpr int NT = DOUT / 32;                 // 16-col tiles per wave

    // ---- GEMM1: ts = relu(hs @ w1 + b1) ----
    {
        const int rr = rb + m;
        const int sw = (rr & 7) << 3;
        bf16x8 a1[4];
#pragma unroll
        for (int s = 0; s < 4; ++s)
            a1[s] = *(const bf16x8*)&hs[rr * 128 + ((s * 32 + ko) ^ sw)];
        f32x4 acc[NT];
#pragma unroll
        for (int nt = 0; nt < NT; ++nt) acc[nt] = (f32x4){0.f, 0.f, 0.f, 0.f};
#pragma unroll
        for (int nt = 0; nt < NT; ++nt) {
            int n = cbase + nt * 16 + m;
#pragma unroll
            for (int s = 0; s < 4; ++s) {
                bf16x8 bf = *(const bf16x8*)&w1t[(size_t)n * 128 + s * 32 + ko];
                acc[nt] = __builtin_amdgcn_mfma_f32_16x16x32_bf16(a1[s], bf, acc[nt], 0, 0, 0);
            }
        }
#pragma unroll
        for (int nt = 0; nt < NT; ++nt) {
            int n = cbase + nt * 16 + m;
            float bias = b1[n];
#pragma unroll
            for (int j2 = 0; j2 < 4; ++j2) {
                int dr = rb + (lane >> 4) * 4 + j2;   // D: col=lane&15, row=(lane>>4)*4+reg
                float v = fmaxf(acc[nt][j2] + bias, 0.f);
                ts[dr * DOUT + (n ^ ((dr & 7) << 3))] = f2bf(v);
            }
        }
    }
    __syncthreads();

    // ---- GEMM2: y = ts @ w2 + b2 ----
    {
        const int rr = rb + m;
        const int sw = (rr & 7) << 3;
        constexpr int KS = DOUT / 32;
        bf16x8 a2[KS];
#pragma unroll
        for (int s = 0; s < KS; ++s)
            a2[s] = *(const bf16x8*)&ts[rr * DOUT + ((s * 32 + ko) ^ sw)];
        f32x4 acc[NT];
#pragma unroll
        for (int nt = 0; nt < NT; ++nt) acc[nt] = (f32x4){0.f, 0.f, 0.f, 0.f};
#pragma unroll
        for (int nt = 0; nt < NT; ++nt) {
            int n = cbase + nt * 16 + m;
#pragma unroll
            for (int s = 0; s < KS; ++s) {
                bf16x8 bf = *(const bf16x8*)&w2t[(size_t)n * DOUT + s * 32 + ko];
                acc[nt] = __builtin_amdgcn_mfma_f32_16x16x32_bf16(a2[s], bf, acc[nt], 0, 0, 0);
            }
        }
#pragma unroll
        for (int nt = 0; nt < NT; ++nt) {
            int n = cbase + nt * 16 + m;
            float bias = b2[n];
#pragma unroll
            for (int j2 = 0; j2 < 4; ++j2) {
                int dr = rb + (lane >> 4) * 4 + j2;
                int node = base + dr;
                if (node < N_NODES) {
                    float v = acc[nt][j2] + bias;
                    if (RELU_OUT) v = fmaxf(v, 0.f);
                    if (F32OUT) ((float*)yout)[(size_t)node * DOUT + n] = v;
                    else        ((u16*)yout)[(size_t)node * DOUT + n] = f2bf(v);
                }
            }
        }
    }
}

// ---------------- global add pool (fp32 in) ----------------
__global__ void pool_kernel(const float* __restrict__ x, const int* __restrict__ batch,
                            const int* __restrict__ flag, float* __restrict__ out) {
    int idx = blockIdx.x * 256 + threadIdx.x;
    int node = idx >> 6;
    int c = idx & 63;
    if (node >= N_NODES) return;
    int w = *flag;
    int g = idx_at(batch, node, w);
    atomicAdd(&out[(size_t)g * 64 + c], x[(size_t)node * 64 + c]);
}

extern "C" void kernel_launch(void* const* d_in, const int* in_sizes, int n_in,
                              void* d_out, int out_size, void* d_ws, size_t ws_size,
                              hipStream_t stream) {
    const float* x     = (const float*)d_in[0];
    const int*   ei    = (const int*)d_in[1];
    const int*   batch = (const int*)d_in[2];
    const float* w1[3] = {(const float*)d_in[3], (const float*)d_in[7],  (const float*)d_in[11]};
    const float* b1[3] = {(const float*)d_in[4], (const float*)d_in[8],  (const float*)d_in[12]};
    const float* w2[3] = {(const float*)d_in[5], (const float*)d_in[9],  (const float*)d_in[13]};
    const float* b2[3] = {(const float*)d_in[6], (const float*)d_in[10], (const float*)d_in[14]};
    float* out = (float*)d_out;

    char* ws = (char*)d_ws;
    int*   cursor  = (int*)(ws + 0);          // 50000 ints (also histogram counts)
    int*   offsets = (int*)(ws + 200192);     // 50001 ints
    int*   bsum    = (int*)(ws + 400640);     // 196 ints
    int*   flag    = (int*)(ws + 401664);     // 1 int
    int*   ssrc    = (int*)(ws + 401920);     // 600000 ints
    u16*   xb      = (u16*)(ws + 2801920);    // 50000*128 bf16
    u16*   yA      = (u16*)(ws + 15601920);   // 50000*128 bf16
    u16*   yB      = (u16*)(ws + 28401920);   // 50000*128 bf16
    float* yF      = (float*)(ws + 2801920);  // 50000*64 f32 (reuses xb region)
    u16*   wts     = (u16*)(ws + 41201920);   // transposed bf16 weights
    u16* w1t0 = wts +      0;   // [128][128]
    u16* w2t0 = wts +  16384;   // [128][128]
    u16* w1t1 = wts +  32768;   // [128][128]
    u16* w2t1 = wts +  49152;   // [128][128]
    u16* w1t2 = wts +  65536;   // [64][128]
    u16* w2t2 = wts +  73728;   // [64][64]

    detect_kernel<<<1, 64, 0, stream>>>(ei, flag);

    (void)hipMemsetAsync(cursor, 0, N_NODES * sizeof(int), stream);
    hist_kernel<<<(N_EDGES + 255) / 256, 256, 0, stream>>>(ei, flag, cursor);
    scan1<<<196, 256, 0, stream>>>(cursor, offsets, bsum);
    scan2<<<1, 256, 0, stream>>>(bsum, 196);
    scan3<<<196, 256, 0, stream>>>(offsets, bsum, cursor);
    scatter_kernel<<<(N_EDGES + 255) / 256, 256, 0, stream>>>(ei, flag, cursor, ssrc);

    cvt_x<<<6250, 256, 0, stream>>>(x, xb);
    cvt_wt<<<dim3(4, 4), 256, 0, stream>>>(w1[0], w1t0, 128, 128);
    cvt_wt<<<dim3(4, 4), 256, 0, stream>>>(w2[0], w2t0, 128, 128);
    cvt_wt<<<dim3(4, 4), 256, 0, stream>>>(w1[1], w1t1, 128, 128);
    cvt_wt<<<dim3(4, 4), 256, 0, stream>>>(w2[1], w2t1, 128, 128);
    cvt_wt<<<dim3(4, 2), 256, 0, stream>>>(w1[2], w1t2, 128, 64);
    cvt_wt<<<dim3(2, 2), 256, 0, stream>>>(w2[2], w2t2, 64, 64);

    const int NB = (N_NODES + 63) / 64;   // 782
    fused_layer<128, 1, 0><<<NB, 512, 0, stream>>>(xb, offsets, ssrc, w1t0, b1[0], w2t0, b2[0], yA);
    fused_layer<128, 1, 0><<<NB, 512, 0, stream>>>(yA, offsets, ssrc, w1t1, b1[1], w2t1, b2[1], yB);
    fused_layer< 64, 0, 1><<<NB, 512, 0, stream>>>(yB, offsets, ssrc, w1t2, b1[2], w2t2, b2[2], yF);

    (void)hipMemsetAsync(out, 0, (size_t)out_size * sizeof(float), stream);
    pool_kernel<<<(N_NODES * 64 + 255) / 256, 256, 0, stream>>>(yF, batch, flag, out);
}